// Round 1
// baseline (1394.782 us; speedup 1.0000x reference)
//
#include <hip/hip_runtime.h>
#include <math.h>

#define V 30000
#define E 200
#define T 100
#define N 2048
#define NITER 100
#define KSTR 112          // padded K_TW row stride in ushorts (224 B, 16B-aligned)
#define EPS_OT 1e-16f
#define EPS_LOG 1e-12f

// ws float offsets
#define OFF_KTW    0            // ushort[V*KSTR] bf16 word-major = 1,680,000 floats
#define OFF_KDT    1680000      // float[N*T]
#define OFF_WW     1884800      // V
#define OFF_DD     1914800      // N
#define OFF_TT     1916848      // 128
#define OFF_PM     1916976      // 128  word-softmax per-block max
#define OFF_PS     1917104      // 128  word-softmax per-block sum
#define OFF_BTW    1917232      // V    softmax(word_weights)
#define OFF_BDT    1947232      // 128  softmax(topic_weights)
#define OFF_ACC    1947360      // NITER*T   TW  K.v accumulators
#define OFF_ACCDT  1957360      // NITER*T   DT  K^T.u accumulators (gated)
#define OFF_VTW    1967360      // V
#define OFF_UDT    1997360      // N
#define OFF_UTW    1999408      // 128
#define OFF_VDT    1999536      // 128
#define OFF_DBL    1999664      // 16 floats = 8 doubles: [0]=dsr_slow [1]=l_dt [2]=l_tw [3]=bow_sum
#define OFF_FLAG   1999680      // int index: theta nonzero
#define OFF_KDTNZ  1999681      // int index: any K_DT nonzero
#define OFF_ARR    1999682      // int[2*NITER]: [k]=TW arrive ctr, [NITER+k]=DT arrive ctr

#define NTW 118                 // TW blocks participating in per-iteration barrier
#define NDT 8                   // DT blocks (gated)

#define LOBF(u) __uint_as_float((u) << 16)
#define HIBF(u) __uint_as_float((u) & 0xffff0000u)

__device__ __forceinline__ unsigned short f2bf(float f) {
    unsigned int u = __float_as_uint(f);
    return (unsigned short)((u + 0x7fffu + ((u >> 16) & 1u)) >> 16);
}
__device__ __forceinline__ float bf2f(unsigned short h) {
    return __uint_as_float(((unsigned int)h) << 16);
}

__device__ __forceinline__ float brsum(float x, float* red8) {
    int tid = threadIdx.x;
    for (int o = 32; o; o >>= 1) x += __shfl_down(x, o, 64);
    __syncthreads();
    if ((tid & 63) == 0) red8[tid >> 6] = x;
    __syncthreads();
    return (red8[0] + red8[1]) + (red8[2] + red8[3]);
}

__device__ __forceinline__ void load_krow(const unsigned short* kg, int j, unsigned* ku) {
    const uint4* kp = (const uint4*)(kg + (size_t)j * KSTR);
    #pragma unroll
    for (int i = 0; i < 12; i++) {
        uint4 q = kp[i];
        ku[4*i] = q.x; ku[4*i+1] = q.y; ku[4*i+2] = q.z; ku[4*i+3] = q.w;
    }
    uint2 q2 = *(const uint2*)(((const unsigned*)kp) + 48);
    ku[48] = q2.x; ku[49] = q2.y;
}

// device-scope sub-grid barrier: per-iteration arrive counter, agent-scope atomics.
// __syncthreads() before arriving drains all of this block's outstanding atomics
// (compiler emits s_waitcnt vmcnt(0) before s_barrier), so partial sums are at the
// coherent point before the release-arrive.
__device__ __forceinline__ void gbar(int* ctr, int n, int tid) {
    __syncthreads();
    if (tid == 0) {
        __hip_atomic_fetch_add(ctr, 1, __ATOMIC_RELEASE, __HIP_MEMORY_SCOPE_AGENT);
        while (__hip_atomic_load(ctr, __ATOMIC_ACQUIRE, __HIP_MEMORY_SCOPE_AGENT) < n)
            __builtin_amdgcn_s_sleep(1);
    }
    __syncthreads();
}

__device__ __forceinline__ float agent_ldf(const float* p) {
    return __hip_atomic_load(p, __ATOMIC_RELAXED, __HIP_MEMORY_SCOPE_AGENT);
}

// ---------- zeroing + row norms + word-softmax partials + topic softmax ----------
__global__ void k_pre(const float* __restrict__ we, const float* __restrict__ de,
                      const float* __restrict__ te, const float* __restrict__ wwgt,
                      const float* __restrict__ twgt, float* ws) {
    __shared__ float red[256];
    int tid = threadIdx.x, b = blockIdx.x;
    int gid = b * 256 + tid;
    if (gid < 2 * NITER * T) ws[OFF_ACC + gid] = 0.f;      // ACC + ACCDT contiguous
    if (gid < 16) ws[OFF_DBL + gid] = 0.f;
    if (gid < 2) ((int*)ws)[OFF_FLAG + gid] = 0;
    if (gid < 2 * NITER) ((int*)ws)[OFF_ARR + gid] = 0;    // barrier arrive counters
    {   // squared row norms
        int r = gid;
        const float* src = nullptr; float* dst = nullptr; int row = 0;
        if (r < V)              { src = we; dst = ws + OFF_WW; row = r; }
        else if (r < V + N)     { src = de; dst = ws + OFF_DD; row = r - V; }
        else if (r < V + N + T) { src = te; dst = ws + OFF_TT; row = r - V - N; }
        if (src) {
            const float4* p = (const float4*)(src + (size_t)row * E);
            float s = 0.f;
            #pragma unroll 10
            for (int i = 0; i < E / 4; i++) { float4 v = p[i]; s += v.x*v.x + v.y*v.y + v.z*v.z + v.w*v.w; }
            dst[row] = s;
        }
    }
    if (b < 118) {  // word-softmax partials
        int j = gid;
        float w = (j < V) ? wwgt[j] : -INFINITY;
        red[tid] = w; __syncthreads();
        for (int s = 128; s > 0; s >>= 1) { if (tid < s) red[tid] = fmaxf(red[tid], red[tid + s]); __syncthreads(); }
        float m = red[0]; __syncthreads();
        float e = (j < V) ? expf(w - m) : 0.f;
        red[tid] = e; __syncthreads();
        for (int s = 128; s > 0; s >>= 1) { if (tid < s) red[tid] += red[tid + s]; __syncthreads(); }
        if (tid == 0) { ws[OFF_PM + b] = m; ws[OFF_PS + b] = red[0]; }
    } else if (b == 120) {  // topic softmax -> b_dt
        float w = (tid < T) ? twgt[tid] : -INFINITY;
        red[tid] = w; __syncthreads();
        for (int s = 128; s > 0; s >>= 1) { if (tid < s) red[tid] = fmaxf(red[tid], red[tid + s]); __syncthreads(); }
        float m = red[0]; __syncthreads();
        float e = (tid < T) ? expf(w - m) : 0.f;
        red[tid] = e; __syncthreads();
        for (int s = 128; s > 0; s >>= 1) { if (tid < s) red[tid] += red[tid + s]; __syncthreads(); }
        if (tid < T) ws[OFF_BDT + tid] = e / red[0];
    }
}

// ---------- merge word-softmax partials -> b_tw ----------
__global__ void k_pre2(const float* __restrict__ wwgt, float* ws) {
    __shared__ float red[128];
    int tid = threadIdx.x, b = blockIdx.x;
    float m = (tid < 118) ? ws[OFF_PM + tid] : -INFINITY;
    if (tid < 128) red[tid] = m;
    __syncthreads();
    for (int s = 64; s > 0; s >>= 1) { if (tid < s) red[tid] = fmaxf(red[tid], red[tid + s]); __syncthreads(); }
    float mw = red[0]; __syncthreads();
    float p = (tid < 118) ? ws[OFF_PS + tid] * expf(ws[OFF_PM + tid] - mw) : 0.f;
    if (tid < 128) red[tid] = p;
    __syncthreads();
    for (int s = 64; s > 0; s >>= 1) { if (tid < s) red[tid] += red[tid + s]; __syncthreads(); }
    float Sw = red[0];
    int j = b * 256 + tid;
    if (j < V) ws[OFF_BTW + j] = expf(wwgt[j] - mw) / Sw;
}

// ---------- K_TW[j][t] = bf16(exp(-2*sqdist)), word-major stride KSTR ----------
__global__ void k_ktw(const float* __restrict__ we, const float* __restrict__ te, float* ws) {
    __shared__ float wt[8][256];
    __shared__ float tp[8][25];
    __shared__ float tts[25];
    int tid = threadIdx.x;
    int j0 = blockIdx.x * 256;
    int t0 = blockIdx.y * 25;
    int j = j0 + tid;
    int jl = (j < V) ? j : V - 1;
    float acc[25];
    #pragma unroll
    for (int i = 0; i < 25; i++) acc[i] = 0.f;
    if (tid < 25) tts[tid] = ws[OFF_TT + t0 + tid];
    for (int kk = 0; kk < E; kk += 8) {
        #pragma unroll
        for (int k = 0; k < 8; k++) wt[k][tid] = we[(size_t)jl * E + kk + k];
        if (tid < 200) { int i = tid >> 3; int k = tid & 7; tp[k][i] = te[(size_t)(t0 + i) * E + kk + k]; }
        __syncthreads();
        #pragma unroll
        for (int k = 0; k < 8; k++) {
            float w = wt[k][tid];
            #pragma unroll
            for (int i = 0; i < 25; i++) acc[i] += tp[k][i] * w;
        }
        __syncthreads();
    }
    if (j < V) {
        float wwj = ws[OFF_WW + j];
        unsigned short* kg = (unsigned short*)(ws + OFF_KTW);
        #pragma unroll
        for (int i = 0; i < 25; i++) {
            float M = tts[i] + wwj - 2.f * acc[i];
            kg[(size_t)j * KSTR + t0 + i] = f2bf(expf(-2.f * M));
        }
    }
}

// ---------- K_DT[n][t] = exp(-3*sqdist), fp32, + any-nonzero flag ----------
__global__ void k_kdt(const float* __restrict__ de, const float* __restrict__ te, float* ws) {
    int gid = blockIdx.x * 256 + threadIdx.x;
    if (gid >= N * T) return;
    int n = gid / T; int t = gid - n * T;
    const float4* dp  = (const float4*)(de + (size_t)n * E);
    const float4* tpp = (const float4*)(te + (size_t)t * E);
    float s = 0.f;
    #pragma unroll 10
    for (int i = 0; i < E / 4; i++) { float4 a = dp[i], b = tpp[i]; s += a.x*b.x + a.y*b.y + a.z*b.z + a.w*b.w; }
    float M = ws[OFF_DD + n] + ws[OFF_TT + t] - 2.f * s;
    float kv = expf(-3.f * M);
    ws[OFF_KDT + gid] = kv;
    unsigned long long m = __ballot(kv != 0.f);
    if (m && (threadIdx.x & 63) == 0) atomicOr(((int*)ws) + OFF_KDTNZ, 1);
}

// ---------- persistent fused sinkhorn: all NITER iterations in ONE dispatch ----------
// blocks 0..117   : TW sinkhorn (K rows resident in registers for all iterations)
//                   + fused final-u / TW-loss epilogue (was k_post TW role)
// blocks 118..245 : bow total sum (no barriers, streams concurrently)
// blocks 246..253 : DT sinkhorn (gated on kdtnz) + fused DT epilogue (was k_post DT)
__global__ __launch_bounds__(256, 1) void k_sink(const float* __restrict__ bow, float* ws) {
    __shared__ float sm[256 * 26];
    __shared__ float pr[256];
    __shared__ float u_sh[100];
    __shared__ float red8[8];
    int tid = threadIdx.x, b = blockIdx.x;
    int* arr = ((int*)ws) + OFF_ARR;

    if (b >= 118 && b < 246) {            // ---- bow role: free-running, no barriers ----
        const float4* b4 = (const float4*)bow;
        // identical chunked arithmetic to the previous version (96 slices of 160000
        // float4) so per-thread fp32 partials stay bit-identical.
        for (int k = 0; k < 96; k++) {
            size_t base = (size_t)k * 160000;
            float s = 0.f;
            for (int i = (b - 118) * 256 + tid; i < 160000; i += 128 * 256) {
                float4 x = b4[base + i]; s += (x.x + x.y) + (x.z + x.w);
            }
            float bs = brsum(s, red8);
            if (tid == 0) atomicAdd((double*)(ws + OFF_DBL) + 3, (double)bs);
        }
        return;
    }

    if (b >= 246) {                       // ---- DT role (gated, own 8-block barrier) ----
        if (((volatile int*)ws)[OFF_KDTNZ] == 0) return;
        int d = (b - 246) * 256 + tid;    // 0..2047
        const float* Kr = ws + OFF_KDT + (size_t)d * T;
        for (int k = 0; k < NITER; k++) {
            if (tid < T) u_sh[tid] = (k == 0) ? 0.f
                : ws[OFF_BDT + tid] / (agent_ldf(ws + OFF_ACCDT + (k - 1) * T + tid) + EPS_OT);
            __syncthreads();
            float u;
            if (k == 0) u = 1.f / N;
            else {
                float s = 0.f;
                #pragma unroll 4
                for (int t = 0; t < T; t++) s += Kr[t] * u_sh[t];
                u = (1.f / N) / (s + EPS_OT);
            }
            #pragma unroll
            for (int c = 0; c < 4; c++) {
                #pragma unroll
                for (int i = 0; i < 25; i++) sm[tid * 26 + i] = Kr[25 * c + i] * u;
                __syncthreads();
                int g = tid >> 5, tl = tid & 31;
                float s2 = 0.f;
                if (tl < 25) {
                    #pragma unroll 8
                    for (int q = 0; q < 32; q++) s2 += sm[(g * 32 + q) * 26 + tl];
                }
                pr[g * 32 + tl] = s2;
                __syncthreads();
                if (tid < 25) {
                    float r = 0.f;
                    #pragma unroll
                    for (int g2 = 0; g2 < 8; g2++) r += pr[g2 * 32 + tid];
                    atomicAdd(&ws[OFF_ACCDT + k * T + 25 * c + tid], r);
                }
                __syncthreads();
            }
            gbar(arr + NITER + k, NDT, tid);
        }
        // ---- fused DT epilogue (was k_post DT role) ----
        if (tid < T) {
            float vf = ws[OFF_BDT + tid] / (agent_ldf(ws + OFF_ACCDT + (NITER - 1) * T + tid) + EPS_OT);
            u_sh[tid] = vf;
            if (b == 246) ws[OFF_VDT + tid] = vf;
        }
        __syncthreads();
        float s = 0.f;
        #pragma unroll 4
        for (int t = 0; t < T; t++) s += Kr[t] * u_sh[t];
        float u = (1.f / N) / (s + EPS_OT);
        ws[OFF_UDT + d] = u;
        float ld = 0.f; int nz = 0;
        for (int t = 0; t < T; t++) {
            float kv = Kr[t];
            if (kv > 0.f) ld += u * kv * u_sh[t] * (-(1.f / 3.f) * logf(kv));
            if ((float)N * u * kv * u_sh[t] != 0.f) nz = 1;
        }
        float ldb = brsum(ld, red8);
        if (tid == 0) atomicAdd((double*)(ws + OFF_DBL) + 1, (double)ldb);
        if (nz) atomicOr(((int*)ws) + OFF_FLAG, 1);
        return;
    }

    // ---- TW role: K row loaded ONCE, kept in registers for all 100 iterations ----
    const unsigned short* kg = (const unsigned short*)(ws + OFF_KTW);
    int j = b * 256 + tid;
    bool oob = (j >= V);
    int jc = oob ? V - 1 : j;
    unsigned ku[50];
    load_krow(kg, jc, ku);
    if (oob) {
        #pragma unroll
        for (int q = 0; q < 50; q++) ku[q] = 0;
    }
    float bj = oob ? 0.f : ws[OFF_BTW + j];
    float v = 0.f;
    for (int k = 0; k < NITER; k++) {
        if (tid < T) u_sh[tid] = (k == 0) ? 0.01f
            : 0.01f / (agent_ldf(ws + OFF_ACC + (k - 1) * T + tid) + EPS_OT);
        __syncthreads();
        float s = 0.f;
        #pragma unroll
        for (int q = 0; q < 50; q++)
            s += LOBF(ku[q]) * u_sh[2 * q] + HIBF(ku[q]) * u_sh[2 * q + 1];
        v = oob ? 0.f : bj / (s + EPS_OT);
        if (k == NITER - 1 && !oob) ws[OFF_VTW + j] = v;
        __syncthreads();
        #pragma unroll
        for (int c = 0; c < 4; c++) {
            #pragma unroll
            for (int i = 0; i < 25; i++) {
                int t = 25 * c + i;
                unsigned w = ku[t >> 1];
                float kt = (t & 1) ? HIBF(w) : LOBF(w);
                sm[tid * 26 + i] = kt * v;
            }
            __syncthreads();
            int g = tid >> 5, tl = tid & 31;
            float s2 = 0.f;
            if (tl < 25) {
                #pragma unroll 8
                for (int q = 0; q < 32; q++) s2 += sm[(g * 32 + q) * 26 + tl];
            }
            pr[g * 32 + tl] = s2;
            __syncthreads();
            if (tid < 25) {
                float r = 0.f;
                #pragma unroll
                for (int g2 = 0; g2 < 8; g2++) r += pr[g2 * 32 + tid];
                atomicAdd(&ws[OFF_ACC + k * T + 25 * c + tid], r);
            }
            __syncthreads();
        }
        gbar(arr + k, NTW, tid);
    }
    // ---- fused TW epilogue (was k_post TW role): final u + TW loss ----
    if (tid < T) {
        float a = agent_ldf(ws + OFF_ACC + (NITER - 1) * T + tid);
        float uf = 0.01f / (a + EPS_OT);
        u_sh[tid] = uf;
        if (b == 0) ws[OFF_UTW + tid] = uf;
    }
    __syncthreads();
    float lt = 0.f;
    if (!oob) {
        #pragma unroll
        for (int q = 0; q < 50; q++) {
            float k0 = LOBF(ku[q]), k1 = HIBF(ku[q]);
            if (k0 > 0.f) lt += u_sh[2 * q]     * k0 * v * (-0.5f * logf(k0));
            if (k1 > 0.f) lt += u_sh[2 * q + 1] * k1 * v * (-0.5f * logf(k1));
        }
    }
    float ltb = brsum(lt, red8);
    if (tid == 0) atomicAdd((double*)(ws + OFF_DBL) + 2, (double)ltb);
}

// ---------- DSR slow path only (theta != 0 somewhere) ----------
__global__ void k_dsr(const float* __restrict__ bow, float* ws) {
    if (*(volatile int*)(((int*)ws) + OFF_FLAG) == 0) return;
    __shared__ float th[32 * T];
    __shared__ float u2[T];
    __shared__ float vd[T];
    __shared__ float red[256];
    __shared__ int flag;
    int tid = threadIdx.x;
    int j0 = blockIdx.x * 256;
    int d0 = blockIdx.y * 32;
    if (tid < T) { vd[tid] = ws[OFF_VDT + tid]; u2[tid] = ws[OFF_UTW + tid]; }
    if (tid == 0) flag = 0;
    __syncthreads();
    bool nz = false;
    for (int idx = tid; idx < 32 * T; idx += 256) {
        int dl = idx / T; int t = idx - dl * T;
        float thv = (float)N * ws[OFF_UDT + d0 + dl] * ws[OFF_KDT + (size_t)(d0 + dl) * T + t] * vd[t];
        th[idx] = thv;
        nz |= (thv != 0.f);
    }
    if (nz) flag = 1;
    __syncthreads();
    int j = j0 + tid;
    float part = 0.f;
    const unsigned short* kg = (const unsigned short*)(ws + OFF_KTW);
    if (flag) {
        float acc[32];
        #pragma unroll
        for (int d = 0; d < 32; d++) acc[d] = 0.f;
        if (j < V) {
            float vj = ws[OFF_VTW + j];
            for (int t = 0; t < T; t++) {
                float kv = bf2f(kg[(size_t)j * KSTR + t]);
                float beta = (float)T * u2[t] * kv * vj;
                #pragma unroll
                for (int d = 0; d < 32; d++) acc[d] += th[d * T + t] * beta;
            }
            for (int d = 0; d < 32; d++)
                part += bow[(size_t)(d0 + d) * V + j] * logf(acc[d] + EPS_LOG);
        }
    } else {
        if (j < V) {
            float sb = 0.f;
            #pragma unroll 8
            for (int d = 0; d < 32; d++) sb += bow[(size_t)(d0 + d) * V + j];
            part = sb * logf(EPS_LOG);
        }
    }
    red[tid] = part; __syncthreads();
    for (int s = 128; s > 0; s >>= 1) { if (tid < s) red[tid] += red[tid + s]; __syncthreads(); }
    if (tid == 0) atomicAdd((double*)(ws + OFF_DBL) + 0, (double)red[0]);
}

// ---------- combine ----------
__global__ void k_finish(float* ws, float* out) {
    if (threadIdx.x == 0 && blockIdx.x == 0) {
        double* dbl = (double*)(ws + OFF_DBL);
        int flag = ((int*)ws)[OFF_FLAG];
        double dsr_sum = flag ? dbl[0] : dbl[3] * (double)logf(EPS_LOG);
        double ldsr = -dsr_sum / (double)N;
        double letp = dbl[1] + dbl[2];
        out[0] = (float)(ldsr + letp);
        out[1] = (float)ldsr;
        out[2] = (float)letp;
    }
}

extern "C" void kernel_launch(void* const* d_in, const int* in_sizes, int n_in,
                              void* d_out, int out_size, void* d_ws, size_t ws_size,
                              hipStream_t stream) {
    const float* bow  = (const float*)d_in[0];
    const float* de   = (const float*)d_in[1];
    const float* we   = (const float*)d_in[2];
    const float* te   = (const float*)d_in[3];
    const float* wwgt = (const float*)d_in[4];
    const float* twgt = (const float*)d_in[5];
    float* out = (float*)d_out;
    float* ws  = (float*)d_ws;

    k_pre<<<128, 256, 0, stream>>>(we, de, te, wwgt, twgt, ws);
    k_pre2<<<118, 256, 0, stream>>>(wwgt, ws);
    k_ktw<<<dim3(118, 4), 256, 0, stream>>>(we, te, ws);
    k_kdt<<<800, 256, 0, stream>>>(de, te, ws);
    // single persistent dispatch replaces 100x k_it + k_post:
    // 118 TW blocks + 128 bow blocks + 8 DT blocks = 254 <= 256 CUs, all co-resident.
    k_sink<<<254, 256, 0, stream>>>(bow, ws);
    k_dsr<<<dim3(118, 64), 256, 0, stream>>>(bow, ws);
    k_finish<<<1, 64, 0, stream>>>(ws, out);
}